// Round 5
// baseline (46.854 us; speedup 1.0000x reference)
//
#include <hip/hip_runtime.h>
#include <hip/hip_bf16.h>
#include <stdint.h>

// LogLinearCDE: out = softmax(W_out @ (y0 * prod_l flows[l]) + b_out)
// flows[l,h] = 1 + sum_c logsigs[l,c]*vf_A[c,h];  y0 = W_in@x0 + b_in
// R5: 3 kernels. (1) pack vf_A to bf16 hi/lo + zero counter. (2) MFMA partial
// products, 2 chunks/block (B-reuse), transposed output ws_pT[h][chunk].
// (3) fused reduce+head: coalesced per-h chunk product, y0, partial logits,
// last-block (threadfence reduction) deterministic logit sum + softmax.

#define LSTEPS 16384
#define HID    4096
#define CC     17
#define NLAB   10
#define NW     16          // packed u32 words per col (K padded to 32 bf16)
#define NCHUNK 256
#define CR     64          // rows per chunk
#define APAD   20          // LDS A row stride in words (80B, 16B-aligned)
#define CPB    2           // chunks per partial block
#define NCG    (NCHUNK/CPB)
#define RBLK   256         // reduce blocks
#define HPB    (HID/RBLK)  // 16 h per reduce block

typedef __attribute__((ext_vector_type(8))) short short8;
typedef __attribute__((ext_vector_type(4))) float f32x4;

static __device__ __forceinline__ unsigned short f2bf(float x) {
  __hip_bfloat16 h = __float2bfloat16(x);
  return *reinterpret_cast<unsigned short*>(&h);
}
static __device__ __forceinline__ float bf2f(unsigned short u) {
  __hip_bfloat16 h; *reinterpret_cast<unsigned short*>(&h) = u;
  return __bfloat162float(h);
}
static __device__ __forceinline__ uint32_t pack_hi(float v0, float v1) {
  return (uint32_t)f2bf(v0) | ((uint32_t)f2bf(v1) << 16);
}
static __device__ __forceinline__ uint32_t pack_lo(float v0, float v1) {
  float r0 = v0 - bf2f(f2bf(v0)), r1 = v1 - bf2f(f2bf(v1));
  return (uint32_t)f2bf(r0) | ((uint32_t)f2bf(r1) << 16);
}

// pre-pass: pack vf_A (C,H) into per-column bf16 hi/lo K-words; zero counter.
__global__ __launch_bounds__(256) void pack_vfA_kernel(
    const float* __restrict__ vfA,
    uint32_t* __restrict__ pBh, uint32_t* __restrict__ pBl,
    uint32_t* __restrict__ counter) {
  if (blockIdx.x == 0 && threadIdx.x == 0) *counter = 0u;
  const int c = blockIdx.x*256 + threadIdx.x;
  float v[2*NW];
  #pragma unroll
  for (int k = 0; k < 2*NW; ++k) v[k] = (k < CC) ? vfA[k*HID + c] : 0.0f;
  #pragma unroll
  for (int j = 0; j < NW; ++j) {
    pBh[(size_t)c*NW + j] = pack_hi(v[2*j], v[2*j+1]);
    pBl[(size_t)c*NW + j] = pack_lo(v[2*j], v[2*j+1]);
  }
}

// partial products over CR-row chunks via MFMA; CPB chunks per block.
__global__ __launch_bounds__(256, 2) void partial_mfma_kernel(
    const float* __restrict__ logsigs, const uint32_t* __restrict__ pBh,
    const uint32_t* __restrict__ pBl, float* __restrict__ ws_pT) {
  const int hb = blockIdx.x;        // 0..3 (1024 cols each)
  const int cg = blockIdx.y;        // 0..NCG-1
  const int chunk0 = cg * CPB;
  const int tid = threadIdx.x;

  __shared__ __align__(16) uint32_t sAh[CPB][CR][APAD], sAl[CPB][CR][APAD];

  // convert CPB chunks of logsig rows to packed bf16 hi/lo words
  const float* __restrict__ src = logsigs + (size_t)chunk0*CR*CC;
  for (int e = tid; e < CPB*CR*NW; e += 256) {
    const int cch = e >> 10;          // / (CR*NW)
    const int r   = (e >> 4) & (CR-1);
    const int j   = e & (NW-1);
    const int k0 = 2*j, k1 = k0 + 1;
    const int rr = cch*CR + r;
    const float v0 = (k0 < CC) ? src[rr*CC + k0] : 0.0f;
    const float v1 = (k1 < CC) ? src[rr*CC + k1] : 0.0f;
    sAh[cch][r][j] = pack_hi(v0, v1);
    sAl[cch][r][j] = pack_lo(v0, v1);
  }
  __syncthreads();

  const int wv = tid >> 6, lane = tid & 63;
  const int g = lane >> 4, cr = lane & 15;

  short8 Ah[CPB][4], Al[CPB][4];
  #pragma unroll
  for (int cc = 0; cc < CPB; ++cc)
    #pragma unroll
    for (int mt = 0; mt < 4; ++mt) {
      const int r = mt*16 + cr;
      Ah[cc][mt] = *reinterpret_cast<const short8*>(&sAh[cc][r][4*g]);
      Al[cc][mt] = *reinterpret_cast<const short8*>(&sAl[cc][r][4*g]);
    }

  const int cbase = hb*1024 + wv*256;
  #pragma unroll 2
  for (int nt = 0; nt < 16; ++nt) {
    const int c = cbase + nt*16 + cr;
    const short8 Bh = *reinterpret_cast<const short8*>(&pBh[(size_t)c*NW + 4*g]);
    const short8 Bl = *reinterpret_cast<const short8*>(&pBl[(size_t)c*NW + 4*g]);
    float pc[CPB];
    #pragma unroll
    for (int cc = 0; cc < CPB; ++cc) {
      float pcol = 1.0f;
      #pragma unroll
      for (int mt = 0; mt < 4; ++mt) {
        f32x4 acc = {0.0f, 0.0f, 0.0f, 0.0f};
        acc = __builtin_amdgcn_mfma_f32_16x16x32_bf16(Ah[cc][mt], Bh, acc, 0, 0, 0);
        acc = __builtin_amdgcn_mfma_f32_16x16x32_bf16(Ah[cc][mt], Bl, acc, 0, 0, 0);
        acc = __builtin_amdgcn_mfma_f32_16x16x32_bf16(Al[cc][mt], Bh, acc, 0, 0, 0);
        pcol *= (1.0f + acc[0]) * (1.0f + acc[1]) * (1.0f + acc[2]) * (1.0f + acc[3]);
      }
      pc[cc] = pcol;
    }
    #pragma unroll
    for (int cc = 0; cc < CPB; ++cc) {
      pc[cc] *= __shfl_xor(pc[cc], 16, 64);
      pc[cc] *= __shfl_xor(pc[cc], 32, 64);
    }
    if (g == 0) {
      float2 w; w.x = pc[0]; w.y = pc[1];
      *reinterpret_cast<float2*>(&ws_pT[(size_t)c*NCHUNK + chunk0]) = w;
    }
  }
}

// fused: per-h product over all chunks (coalesced), y0, logits, softmax.
__global__ __launch_bounds__(256) void reduce_head_kernel(
    const float* __restrict__ ws_pT, const float* __restrict__ Win,
    const float* __restrict__ bin,  const float* __restrict__ x0,
    const float* __restrict__ Wout, const float* __restrict__ bout,
    float* __restrict__ ws_lp, uint32_t* __restrict__ counter,
    float* __restrict__ out) {
  const int b = blockIdx.x, tid = threadIdx.x;
  const int h0 = b * HPB;
  const int hh = tid >> 4, sl = tid & 15;

  __shared__ float sp[HPB][17];
  __shared__ float sy[HPB];
  __shared__ float slog[NLAB];
  __shared__ bool isLast;

  // slice product: 16 contiguous chunk-values per thread, coalesced 16KB/block
  {
    const float4* __restrict__ src =
        reinterpret_cast<const float4*>(ws_pT + (size_t)(h0+hh)*NCHUNK + sl*16);
    float4 a = src[0], bq = src[1], cq = src[2], dq = src[3];
    float p = ((a.x*a.y)*(a.z*a.w)) * ((bq.x*bq.y)*(bq.z*bq.w))
            * ((cq.x*cq.y)*(cq.z*cq.w)) * ((dq.x*dq.y)*(dq.z*dq.w));
    sp[hh][sl] = p;
  }
  __syncthreads();

  if (tid < HPB) {
    float P = 1.0f;
    #pragma unroll
    for (int s = 0; s < 16; ++s) P *= sp[tid][s];
    const int h = h0 + tid;
    const float4* __restrict__ wrow = reinterpret_cast<const float4*>(Win + (size_t)h*16);
    float y = bin[h];
    #pragma unroll
    for (int q = 0; q < 4; ++q) {
      float4 w = wrow[q];
      y = fmaf(w.x, x0[q*4+0], y);
      y = fmaf(w.y, x0[q*4+1], y);
      y = fmaf(w.z, x0[q*4+2], y);
      y = fmaf(w.w, x0[q*4+3], y);
    }
    sy[tid] = y * P;
  }
  __syncthreads();

  // partial logits for this block's 16 h (fixed shfl order -> deterministic)
  if (tid < NLAB*HPB) {                     // 160 threads
    const int j = tid >> 4, k = tid & 15;
    float v = Wout[(size_t)j*HID + h0 + k] * sy[k];
    v += __shfl_xor(v, 1, 64);
    v += __shfl_xor(v, 2, 64);
    v += __shfl_xor(v, 4, 64);
    v += __shfl_xor(v, 8, 64);
    if (k == 0) ws_lp[b*16 + j] = v;
  }
  __threadfence();
  __syncthreads();
  if (tid == 0) isLast = (atomicAdd(counter, 1u) == RBLK - 1);
  __syncthreads();

  if (isLast) {
    __threadfence();
    if (tid < NLAB*16) {                    // j x 16 block-slices
      const int j = tid >> 4, s = tid & 15;
      float acc = 0.0f;
      #pragma unroll
      for (int bb = 0; bb < 16; ++bb)
        acc += __hip_atomic_load(&ws_lp[(s*16 + bb)*16 + j],
                                 __ATOMIC_RELAXED, __HIP_MEMORY_SCOPE_AGENT);
      acc += __shfl_xor(acc, 1, 64);
      acc += __shfl_xor(acc, 2, 64);
      acc += __shfl_xor(acc, 4, 64);
      acc += __shfl_xor(acc, 8, 64);
      if (s == 0) slog[j] = acc + bout[j];
    }
    __syncthreads();
    if (tid == 0) {
      float m = slog[0];
      #pragma unroll
      for (int j = 1; j < NLAB; ++j) m = fmaxf(m, slog[j]);
      float ssum = 0.0f;
      float e[NLAB];
      #pragma unroll
      for (int j = 0; j < NLAB; ++j) { e[j] = __expf(slog[j] - m); ssum += e[j]; }
      const float inv = 1.0f / ssum;
      #pragma unroll
      for (int j = 0; j < NLAB; ++j) out[j] = e[j] * inv;
    }
  }
}

extern "C" void kernel_launch(void* const* d_in, const int* in_sizes, int n_in,
                              void* d_out, int out_size, void* d_ws, size_t ws_size,
                              hipStream_t stream) {
  // inputs: 0=ts (unused), 1=logsigs (L,C), 2=x0 (D), 3=W_in (H,D), 4=b_in (H),
  //         5=vf_A (C,H), 6=W_out (10,H), 7=b_out (10)
  const float* logsigs = (const float*)d_in[1];
  const float* x0      = (const float*)d_in[2];
  const float* Win     = (const float*)d_in[3];
  const float* bin     = (const float*)d_in[4];
  const float* vfA     = (const float*)d_in[5];
  const float* Wout    = (const float*)d_in[6];
  const float* bout    = (const float*)d_in[7];
  float* out = (float*)d_out;

  // workspace layout (16B-aligned slices)
  float*    ws_pT = (float*)d_ws;                       // HID*NCHUNK f32 = 4MB
  uint32_t* pBh   = (uint32_t*)(ws_pT + (size_t)HID*NCHUNK); // 256KB
  uint32_t* pBl   = pBh + (size_t)HID*NW;                    // 256KB
  float*    ws_lp = (float*)(pBl + (size_t)HID*NW);          // RBLK*16 f32
  uint32_t* cnt   = (uint32_t*)(ws_lp + (size_t)RBLK*16);

  pack_vfA_kernel<<<HID/256, 256, 0, stream>>>(vfA, pBh, pBl, cnt);
  partial_mfma_kernel<<<dim3(4, NCG), 256, 0, stream>>>(logsigs, pBh, pBl, ws_pT);
  reduce_head_kernel<<<RBLK, 256, 0, stream>>>(ws_pT, Win, bin, x0, Wout, bout,
                                               ws_lp, cnt, out);
}